// Round 1
// baseline (889.200 us; speedup 1.0000x reference)
//
#include <hip/hip_runtime.h>
#include <math.h>

// ---------------------------------------------------------------------------
// CoarseMVSNet fused implementation.
//  setup_mats_kernel : compose K@E per view, invert ref, P = src @ inv(ref)
//  transpose_cl_kernel: (V,C,H,W) -> (V,H,W,C) channel-last copy in ws
//  stage_kernel      : fully fused warp + variance + conv3d + softmax head
// ---------------------------------------------------------------------------

__global__ void setup_mats_kernel(const float* __restrict__ proj1,
                                  const float* __restrict__ proj2,
                                  const float* __restrict__ depthv, int nd,
                                  float* __restrict__ ws) {
  if (threadIdx.x != 0 || blockIdx.x != 0) return;
  for (int s = 0; s < 2; ++s) {
    const float* P = s ? proj2 : proj1;  // (3,2,4,4) flat
    double comp[3][4][4];
    for (int v = 0; v < 3; ++v) {
      const float* E = P + v * 32;       // [v][0]
      const float* K = P + v * 32 + 16;  // [v][1]
      for (int r = 0; r < 3; ++r)
        for (int c = 0; c < 4; ++c) {
          double acc = 0.0;
          for (int k = 0; k < 3; ++k) acc += (double)K[r * 4 + k] * (double)E[k * 4 + c];
          comp[v][r][c] = acc;
        }
      for (int c = 0; c < 4; ++c) comp[v][3][c] = (double)E[12 + c];
    }
    // invert comp[0] (Gauss-Jordan, partial pivot)
    double a[4][8];
    for (int r = 0; r < 4; ++r)
      for (int c = 0; c < 4; ++c) {
        a[r][c] = comp[0][r][c];
        a[r][4 + c] = (r == c) ? 1.0 : 0.0;
      }
    for (int col = 0; col < 4; ++col) {
      int piv = col;
      double best = fabs(a[col][col]);
      for (int r = col + 1; r < 4; ++r) {
        double t = fabs(a[r][col]);
        if (t > best) { best = t; piv = r; }
      }
      if (piv != col)
        for (int c = 0; c < 8; ++c) { double t = a[col][c]; a[col][c] = a[piv][c]; a[piv][c] = t; }
      double dv = a[col][col];
      for (int c = 0; c < 8; ++c) a[col][c] /= dv;
      for (int r = 0; r < 4; ++r)
        if (r != col) {
          double f = a[r][col];
          if (f != 0.0)
            for (int c = 0; c < 8; ++c) a[r][c] -= f * a[col][c];
        }
    }
    for (int v = 1; v < 3; ++v) {
      double Pm[3][4];
      for (int r = 0; r < 3; ++r)
        for (int c = 0; c < 4; ++c) {
          double acc = 0.0;
          for (int k = 0; k < 4; ++k) acc += comp[v][r][k] * a[k][4 + c];
          Pm[r][c] = acc;
        }
      float* o = ws + s * 24 + (v - 1) * 12;
      o[0] = (float)Pm[0][0]; o[1] = (float)Pm[0][1]; o[2] = (float)Pm[0][2];
      o[3] = (float)Pm[1][0]; o[4] = (float)Pm[1][1]; o[5] = (float)Pm[1][2];
      o[6] = (float)Pm[2][0]; o[7] = (float)Pm[2][1]; o[8] = (float)Pm[2][2];
      o[9] = (float)Pm[0][3]; o[10] = (float)Pm[1][3]; o[11] = (float)Pm[2][3];
    }
  }
  ws[48] = depthv[0];
  ws[49] = (depthv[nd - 1] - depthv[0]) / 47.0f;  // (dmax-dmin)/(ND1-1)
}

__global__ void transpose_cl_kernel(const float* __restrict__ in, float* __restrict__ out,
                                    int C, int H, int W) {
  int total = 3 * C * H * W;
  int idx = blockIdx.x * 256 + threadIdx.x;
  if (idx >= total) return;
  int c = idx % C;
  int t = idx / C;
  int w = t % W;
  int t2 = t / W;
  int h = t2 % H;
  int v = t2 / H;
  out[idx] = in[((size_t)(v * C + c) * H + h) * W + w];
}

// C channels, D depth samples, TH x TW output tile, H x W image.
// STAGE2: per-pixel depth samples from upsampled d1/v1. CL: channel-last feats.
template <int C, int D, int TH, int TW, int H, int W, bool STAGE2, bool CL>
__launch_bounds__(256)
__global__ void stage_kernel(const float* __restrict__ feats,
                             const float* __restrict__ wconv,
                             const float* __restrict__ bconv,
                             const float* __restrict__ mats,
                             const float* __restrict__ dpar,
                             const float* __restrict__ prev_d,
                             const float* __restrict__ prev_v,
                             float* __restrict__ out_d,
                             float* __restrict__ out_c,
                             float* __restrict__ out_v) {
  constexpr int HB = TH + 2, WB = TW + 2, HALO = HB * WB, NPX = TH * TW;
  constexpr int HP = HALO + 1;  // pad: conv reads stride HP -> conflict-free
  constexpr int C4 = C / 4;
  constexpr int CG = C / 4;     // channels per conv thread (4 groups)

  __shared__ float s_var[C * HP];
  __shared__ float s_cost[D * NPX];
  __shared__ float s_w[C * 27];
  __shared__ float s_rx[2][HALO], s_ry[2][HALO], s_rz[2][HALO];
  __shared__ float s_w00[2][HALO], s_w10[2][HALO], s_w01[2][HALO], s_w11[2][HALO];
  __shared__ int s_i00[2][HALO], s_i10[2][HALO], s_i01[2][HALO], s_i11[2][HALO];
  __shared__ int s_gidx[HALO];
  __shared__ float s_dbase[HALO], s_dstep[HALO];
  __shared__ unsigned char s_inb[HALO];

  const int tid = threadIdx.x;
  const int h0 = blockIdx.y * TH;
  const int w0 = blockIdx.x * TW;

  for (int i = tid; i < C * 27; i += 256) s_w[i] = wconv[i];

  // per-halo-pixel precompute: rot@[x,y,1] per view; depth sample base/step
  for (int i = tid; i < HALO; i += 256) {
    int hy = i / WB, hx = i - hy * WB;
    int gy = h0 + hy - 1, gx = w0 + hx - 1;
    bool inb = (gy >= 0) && (gy < H) && (gx >= 0) && (gx < W);
    s_inb[i] = inb ? 1 : 0;
    s_gidx[i] = inb ? (gy * W + gx) : 0;
    float fx = (float)gx, fy = (float)gy;
#pragma unroll
    for (int v = 0; v < 2; ++v) {
      const float* M = mats + v * 12;
      s_rx[v][i] = M[0] * fx + M[1] * fy + M[2];
      s_ry[v][i] = M[3] * fx + M[4] * fy + M[5];
      s_rz[v][i] = M[6] * fx + M[7] * fy + M[8];
    }
    if constexpr (STAGE2) {
      constexpr int SH = H / 2, SW = W / 2;
      // jax.image.resize bilinear 2x: src = (i+0.5)*0.5-0.5, edge-clamped
      float syf = 0.5f * (float)gy - 0.25f;
      float sxf = 0.5f * (float)gx - 0.25f;
      syf = fminf(fmaxf(syf, 0.0f), (float)(SH - 1));
      sxf = fminf(fmaxf(sxf, 0.0f), (float)(SW - 1));
      int sy0 = (int)syf, sx0 = (int)sxf;
      float fy2 = syf - (float)sy0, fx2 = sxf - (float)sx0;
      int sy1 = min(sy0 + 1, SH - 1), sx1 = min(sx0 + 1, SW - 1);
      int j00 = sy0 * SW + sx0, j01 = sy0 * SW + sx1;
      int j10 = sy1 * SW + sx0, j11 = sy1 * SW + sx1;
      float cd = (prev_d[j00] * (1.f - fx2) + prev_d[j01] * fx2) * (1.f - fy2) +
                 (prev_d[j10] * (1.f - fx2) + prev_d[j11] * fx2) * fy2;
      float cv = (prev_v[j00] * (1.f - fx2) + prev_v[j01] * fx2) * (1.f - fy2) +
                 (prev_v[j10] * (1.f - fx2) + prev_v[j11] * fx2) * fy2;
      float lo = -fminf(cd, cv);
      s_dbase[i] = cd + lo + 1e-12f;
      s_dstep[i] = (cv - lo) / (float)(D - 1);
    } else {
      s_dbase[i] = dpar[0];
      s_dstep[i] = dpar[1];
    }
  }
  {
    float bias = bconv[0];
    for (int i = tid; i < D * NPX; i += 256) s_cost[i] = bias;
  }
  __syncthreads();

  // scatter conv contribution of variance slice ds into cost[ds-1..ds+1]
  auto conv_accum = [&](int ds) {
    for (int i = tid; i < NPX * 4; i += 256) {
      int grp = i / NPX, opx = i - grp * NPX;  // grp wave-uniform (NPX=64)
      int py = opx / TW, pxx = opx - py * TW;
      float a0 = 0.f, a1 = 0.f, a2 = 0.f;  // kd = 0,1,2
      int cbase = grp * CG;
#pragma unroll
      for (int kh = 0; kh < 3; ++kh) {
#pragma unroll
        for (int kw = 0; kw < 3; ++kw) {
          int hp = (py + kh) * WB + (pxx + kw);
#pragma unroll
          for (int cc = 0; cc < CG; ++cc) {
            int c = cbase + cc;
            float vv = s_var[c * HP + hp];
            const float* wp = s_w + c * 27 + kh * 3 + kw;
            a0 += vv * wp[0];
            a1 += vv * wp[9];
            a2 += vv * wp[18];
          }
        }
      }
      if (ds + 1 < D) atomicAdd(&s_cost[(ds + 1) * NPX + opx], a0);
      atomicAdd(&s_cost[ds * NPX + opx], a1);
      if (ds - 1 >= 0) atomicAdd(&s_cost[(ds - 1) * NPX + opx], a2);
    }
  };

  for (int d = 0; d < D; ++d) {
    if (d > 0) conv_accum(d - 1);  // same barrier interval as coords (disjoint LDS)
    // warp coordinates for this depth slice, both src views
    for (int i = tid; i < 2 * HALO; i += 256) {
      int v = (i >= HALO) ? 1 : 0;
      int px = i - v * HALO;
      float dep = s_dbase[px] + (float)d * s_dstep[px];
      const float* M = mats + v * 12;
      float X = s_rx[v][px] * dep + M[9];
      float Y = s_ry[v][px] * dep + M[10];
      float Z = s_rz[v][px] * dep + M[11];
      float xz = X / Z, yz = Y / Z;
      float gxn = xz * (2.0f / (float)(W - 1)) - 1.0f;
      float gyn = yz * (2.0f / (float)(H - 1)) - 1.0f;
      float ix = ((gxn + 1.0f) * (float)W - 1.0f) * 0.5f;
      float iy = ((gyn + 1.0f) * (float)H - 1.0f) * 0.5f;
      float x0f = floorf(ix), y0f = floorf(iy);
      float wx = ix - x0f, wy = iy - y0f;
      float x1f = x0f + 1.0f, y1f = y0f + 1.0f;
      bool vx0 = (x0f >= 0.0f) && (x0f <= (float)(W - 1));
      bool vx1 = (x1f >= 0.0f) && (x1f <= (float)(W - 1));
      bool vy0 = (y0f >= 0.0f) && (y0f <= (float)(H - 1));
      bool vy1 = (y1f >= 0.0f) && (y1f <= (float)(H - 1));
      int xc0 = (int)fminf(fmaxf(x0f, 0.0f), (float)(W - 1));
      int xc1 = (int)fminf(fmaxf(x1f, 0.0f), (float)(W - 1));
      int yc0 = (int)fminf(fmaxf(y0f, 0.0f), (float)(H - 1));
      int yc1 = (int)fminf(fmaxf(y1f, 0.0f), (float)(H - 1));
      s_i00[v][px] = yc0 * W + xc0;
      s_i10[v][px] = yc0 * W + xc1;
      s_i01[v][px] = yc1 * W + xc0;
      s_i11[v][px] = yc1 * W + xc1;
      float wxm = 1.0f - wx, wym = 1.0f - wy;
      s_w00[v][px] = (vx0 && vy0) ? wxm * wym : 0.0f;
      s_w10[v][px] = (vx1 && vy0) ? wx * wym : 0.0f;
      s_w01[v][px] = (vx0 && vy1) ? wxm * wy : 0.0f;
      s_w11[v][px] = (vx1 && vy1) ? wx * wy : 0.0f;
    }
    __syncthreads();
    // variance slice: ref + 2 warped views, E[x^2]-E[x]^2
    if constexpr (CL) {
      for (int i = tid; i < HALO * C4; i += 256) {
        int cg = i / HALO, px = i - cg * HALO;
        float o0 = 0.f, o1 = 0.f, o2 = 0.f, o3 = 0.f;
        if (s_inb[px]) {
          const float4* fp = (const float4*)feats;
          float4 r = fp[(size_t)s_gidx[px] * C4 + cg];
          float s0 = r.x, s1 = r.y, s2 = r.z, s3 = r.w;
          float q0 = r.x * r.x, q1 = r.y * r.y, q2 = r.z * r.z, q3 = r.w * r.w;
#pragma unroll
          for (int v = 0; v < 2; ++v) {
            const float4* fv = fp + (size_t)(v + 1) * H * W * C4 + cg;
            float a00 = s_w00[v][px], a10 = s_w10[v][px];
            float a01 = s_w01[v][px], a11 = s_w11[v][px];
            float4 p00 = fv[(size_t)s_i00[v][px] * C4];
            float4 p10 = fv[(size_t)s_i10[v][px] * C4];
            float4 p01 = fv[(size_t)s_i01[v][px] * C4];
            float4 p11 = fv[(size_t)s_i11[v][px] * C4];
            float g0 = a00 * p00.x + a10 * p10.x + a01 * p01.x + a11 * p11.x;
            float g1 = a00 * p00.y + a10 * p10.y + a01 * p01.y + a11 * p11.y;
            float g2 = a00 * p00.z + a10 * p10.z + a01 * p01.z + a11 * p11.z;
            float g3 = a00 * p00.w + a10 * p10.w + a01 * p01.w + a11 * p11.w;
            s0 += g0; q0 += g0 * g0;
            s1 += g1; q1 += g1 * g1;
            s2 += g2; q2 += g2 * g2;
            s3 += g3; q3 += g3 * g3;
          }
          float m;
          m = s0 / 3.0f; o0 = q0 / 3.0f - m * m;
          m = s1 / 3.0f; o1 = q1 / 3.0f - m * m;
          m = s2 / 3.0f; o2 = q2 / 3.0f - m * m;
          m = s3 / 3.0f; o3 = q3 / 3.0f - m * m;
        }
        int cb = cg * 4;
        s_var[(cb + 0) * HP + px] = o0;
        s_var[(cb + 1) * HP + px] = o1;
        s_var[(cb + 2) * HP + px] = o2;
        s_var[(cb + 3) * HP + px] = o3;
      }
    } else {
      for (int i = tid; i < HALO * C; i += 256) {
        int c = i / HALO, px = i - c * HALO;
        float var = 0.f;
        if (s_inb[px]) {
          const float* f0 = feats + (size_t)c * (H * W);
          float rr = f0[s_gidx[px]];
          float sum = rr, ssq = rr * rr;
#pragma unroll
          for (int v = 0; v < 2; ++v) {
            const float* fv = feats + ((size_t)(v + 1) * C + c) * (H * W);
            float val = s_w00[v][px] * fv[s_i00[v][px]] + s_w10[v][px] * fv[s_i10[v][px]] +
                        s_w01[v][px] * fv[s_i01[v][px]] + s_w11[v][px] * fv[s_i11[v][px]];
            sum += val;
            ssq += val * val;
          }
          float m = sum / 3.0f;
          var = ssq / 3.0f - m * m;
        }
        s_var[c * HP + px] = var;
      }
    }
    __syncthreads();
  }
  conv_accum(D - 1);
  __syncthreads();

  // epilogue: softmax over D, depth regression, conf (4-tap window), exp-var
  if (tid < NPX) {
    const int opx = tid;
    const int py = opx / TW, pxx = opx - py * TW;
    const int hp = (py + 1) * WB + (pxx + 1);
    const float base = s_dbase[hp], st = s_dstep[hp];
    float mx = -3.0e38f;
    for (int dd = 0; dd < D; ++dd) mx = fmaxf(mx, s_cost[dd * NPX + opx]);
    float se = 0.f;
    for (int dd = 0; dd < D; ++dd) {
      float e = expf(s_cost[dd * NPX + opx] - mx);
      s_cost[dd * NPX + opx] = e;
      se += e;
    }
    float depth = 0.f, dif = 0.f;
    for (int dd = 0; dd < D; ++dd) {
      float p = s_cost[dd * NPX + opx] / se;
      s_cost[dd * NPX + opx] = p;
      depth += p * (base + (float)dd * st);
      dif += p * (float)dd;
    }
    int di = (int)dif;
    di = min(max(di, 0), D - 1);
    float conf = 0.f;
    for (int k = di - 1; k <= di + 2; ++k)
      if (k >= 0 && k < D) conf += s_cost[k * NPX + opx];
    float ev = 0.f;
    for (int dd = 0; dd < D; ++dd) {
      float sv = base + (float)dd * st - depth;
      ev += sv * sv * s_cost[dd * NPX + opx];
    }
    ev = 1.5f * sqrtf(ev);
    int gy = h0 + py, gx = w0 + pxx;
    out_d[gy * W + gx] = depth;
    out_c[gy * W + gx] = conf;
    out_v[gy * W + gx] = ev;
  }
}

extern "C" void kernel_launch(void* const* d_in, const int* in_sizes, int n_in,
                              void* d_out, int out_size, void* d_ws, size_t ws_size,
                              hipStream_t stream) {
  const float* feats1 = (const float*)d_in[0];
  const float* feats2 = (const float*)d_in[1];
  const float* proj1 = (const float*)d_in[2];
  const float* proj2 = (const float*)d_in[3];
  const float* depthv = (const float*)d_in[4];
  const float* w1 = (const float*)d_in[6];
  const float* b1 = (const float*)d_in[7];
  const float* w2 = (const float*)d_in[8];
  const float* b2 = (const float*)d_in[9];
  float* out = (float*)d_out;
  float* ws = (float*)d_ws;

  const int nd = in_sizes[4];
  const size_t F1 = (size_t)3 * 32 * 128 * 160;
  const size_t F2 = (size_t)3 * 16 * 256 * 320;
  const bool cl = ws_size >= (64 + F1 + F2) * sizeof(float);

  setup_mats_kernel<<<1, 64, 0, stream>>>(proj1, proj2, depthv, nd, ws);

  float* d1 = out;
  float* c1 = out + 20480;
  float* v1 = out + 40960;
  float* d2 = out + 61440;
  float* c2 = out + 143360;
  float* v2 = out + 225280;

  dim3 g1(160 / 8, 128 / 8), g2(320 / 8, 256 / 8);

  if (cl) {
    float* f1t = ws + 64;
    float* f2t = ws + 64 + F1;
    transpose_cl_kernel<<<(int)((F1 + 255) / 256), 256, 0, stream>>>(feats1, f1t, 32, 128, 160);
    transpose_cl_kernel<<<(int)((F2 + 255) / 256), 256, 0, stream>>>(feats2, f2t, 16, 256, 320);
    stage_kernel<32, 48, 8, 8, 128, 160, false, true><<<g1, 256, 0, stream>>>(
        f1t, w1, b1, ws, ws + 48, nullptr, nullptr, d1, c1, v1);
    stage_kernel<16, 8, 8, 8, 256, 320, true, true><<<g2, 256, 0, stream>>>(
        f2t, w2, b2, ws + 24, ws + 48, d1, v1, d2, c2, v2);
  } else {
    stage_kernel<32, 48, 8, 8, 128, 160, false, false><<<g1, 256, 0, stream>>>(
        feats1, w1, b1, ws, ws + 48, nullptr, nullptr, d1, c1, v1);
    stage_kernel<16, 8, 8, 8, 256, 320, true, false><<<g2, 256, 0, stream>>>(
        feats2, w2, b2, ws + 24, ws + 48, d1, v1, d2, c2, v2);
  }
}